// Round 1
// 391.327 us; speedup vs baseline: 1.0226x; 1.0226x over previous
//
#include <hip/hip_runtime.h>
#include <math.h>

#define DEVFN __global__ __launch_bounds__(256)

namespace {
constexpr int LL  = 128;   // L
constexpr int MM2 = 255;   // 2L-1
constexpr int NT  = 256;   // ntheta
constexpr int NP  = 512;   // nphi
constexpr int NC  = 32;    // C_IN
constexpr int NO  = 32;    // C_OUT
constexpr float TWO_PI = 6.283185307179586476925286766559f;
}

typedef short v8s __attribute__((ext_vector_type(8)));   // 8 bf16 (4 VGPRs)
typedef float v4f __attribute__((ext_vector_type(4)));   // 4 fp32 acc

__device__ inline unsigned short f2bf(float f) {
  unsigned int u = __float_as_uint(f);
  return (unsigned short)((u + 0x7FFFu + ((u >> 16) & 1u)) >> 16);  // RNE
}

// ---------------------------------------------------------------- KP: prep (twiddles + x transpose)
DEVFN void kp_prep(const float* __restrict__ x, unsigned short* __restrict__ tw1t,
                   unsigned short* __restrict__ vt, unsigned short* __restrict__ xb) {
  __shared__ float sm[32][65];
  const int bid = blockIdx.x;
  const int tid = threadIdx.x;
  const float phi = TWO_PI / (float)NP;
  if (bid < 512) {
    const int idx = bid * 256 + tid;  // 0..131071
    const float fs = TWO_PI / (float)NP;
    {
      const int n = idx >> 9, p = idx & 511;
      const int m = n >> 1;
      const int k = (m * p) & (NP - 1);
      float s, c;
      sincosf(phi * (float)k, &s, &c);
      tw1t[idx] = f2bf((n & 1) ? (-s * fs) : (c * fs));
    }
    {
      const int p = idx >> 8, k = idx & 255;
      const int m = k >> 1;
      const int kk = (m * p) & (NP - 1);
      float s, c;
      sincosf(phi * (float)kk, &s, &c);
      vt[idx] = f2bf((k & 1) ? s : c);
    }
  } else {
    const int q = bid - 512;           // 0..2047
    const int t = q >> 3;
    const int p0 = (q & 7) * 64;
#pragma unroll
    for (int i = 0; i < 8; ++i) {
      const int idx = tid + i * 256;
      const int p = idx >> 5, c = idx & 31;
      sm[c][p] = x[((size_t)t * NP + p0 + p) * NC + c];
    }
    __syncthreads();
    const int c = tid >> 3, pg = tid & 7;
    unsigned short pk[8];
#pragma unroll
    for (int u = 0; u < 8; ++u) pk[u] = f2bf(sm[c][pg * 8 + u]);
    *(uint4*)(xb + ((size_t)(t * 32 + c)) * NP + p0 + pg * 8) = *(const uint4*)pk;
  }
}

// ---------------------------------------------------------------- K1: forward DFT via MFMA
// C[r][n] = sum_p Xb[r][p] * tw1t[n][p];  fw{r,i}[m][t][c] = C * wg[t]
// M=8192, N=256, K=512.  Tile BM=128 x BN=64 -> grid (64,4) = 256 blocks (full GPU).
DEVFN void k1_mfma(const unsigned short* __restrict__ xb,
                   const unsigned short* __restrict__ tw1t,
                   const float* __restrict__ wg,
                   float* __restrict__ fwr, float* __restrict__ fwi) {
  __shared__ unsigned short As[128 * 32];
  __shared__ unsigned short Bs[64 * 32];
  const int tid = threadIdx.x;
  const int r0 = blockIdx.x * 128;
  const int n0 = blockIdx.y * 64;
  const int wid = tid >> 6, lane = tid & 63;
  const int wm = wid & 1, wn = wid >> 1;   // 2x2 waves, wave tile 64(M) x 32(N)
  v4f acc[4][2];
#pragma unroll
  for (int i = 0; i < 4; ++i)
#pragma unroll
    for (int j = 0; j < 2; ++j) {
      acc[i][j][0] = 0.f; acc[i][j][1] = 0.f; acc[i][j][2] = 0.f; acc[i][j][3] = 0.f;
    }
  const int lr = lane & 15, lk = (lane >> 4) * 8;
  for (int k0 = 0; k0 < 512; k0 += 32) {
#pragma unroll
    for (int s = 0; s < 3; ++s) {
      const int chunk = tid + s * 256;      // 768 chunks x 16B (A:512, B:256)
      if (chunk < 512) {
        const int row = chunk >> 2, c16 = chunk & 3;
        *(uint4*)&As[row * 32 + c16 * 8] =
            *(const uint4*)&xb[(size_t)(r0 + row) * 512 + k0 + c16 * 8];
      } else {
        const int bc = chunk - 512;
        const int row = bc >> 2, c16 = bc & 3;
        *(uint4*)&Bs[row * 32 + c16 * 8] =
            *(const uint4*)&tw1t[(size_t)(n0 + row) * 512 + k0 + c16 * 8];
      }
    }
    __syncthreads();
    v8s af[4], bf[2];
#pragma unroll
    for (int i = 0; i < 4; ++i) af[i] = *(const v8s*)&As[(wm * 64 + i * 16 + lr) * 32 + lk];
#pragma unroll
    for (int j = 0; j < 2; ++j) bf[j] = *(const v8s*)&Bs[(wn * 32 + j * 16 + lr) * 32 + lk];
#pragma unroll
    for (int i = 0; i < 4; ++i)
#pragma unroll
      for (int j = 0; j < 2; ++j)
        acc[i][j] = __builtin_amdgcn_mfma_f32_16x16x32_bf16(af[i], bf[j], acc[i][j], 0, 0, 0);
    __syncthreads();
  }
  const int lrow = (lane >> 4) * 4;
#pragma unroll
  for (int i = 0; i < 4; ++i) {
    const int rbase = r0 + wm * 64 + i * 16 + lrow;
    const int t = rbase >> 5, c0 = rbase & 31;
    const float w = wg[t];
#pragma unroll
    for (int j = 0; j < 2; ++j) {
      const int n = n0 + wn * 32 + j * 16 + lr;
      const int mI = n >> 1;
      float* dst = (n & 1) ? fwi : fwr;
      float4 v = {acc[i][j][0] * w, acc[i][j][1] * w, acc[i][j][2] * w, acc[i][j][3] * w};
      *(float4*)&dst[((size_t)mI * NT + t) * NC + c0] = v;
    }
  }
}

// ---------------------------------------------------------------- K23: fused flm + channel mix
// One wave per (m, l>=m).  Phase 1: flm[c] reduction over t (lane = stream*32 + c),
// handoff through 64-float LDS slice.  Phase 2: weight contraction (lane = half*32 + o),
// identical math to the old k3.  Bijective XCD swizzle: each XCD owns 16 contiguous m
// -> per-XCD fw footprint 1 MB (L2-resident) instead of 8 MB (thrash).
DEVFN void k23(const float* __restrict__ leg, const float* __restrict__ fwr,
               const float* __restrict__ fwi, const float* __restrict__ wr,
               const float* __restrict__ wi, float* __restrict__ ya,
               float* __restrict__ yb) {
  __shared__ float sf[4][64];
  const int fid  = blockIdx.x + (int)blockIdx.y * 128;   // grid (128,32) -> 0..4095
  const int wid4 = (fid & 7) * 512 + (fid >> 3);         // XCD k -> [k*512,(k+1)*512)
  const int m  = wid4 >> 5;                              // 16 m per XCD
  const int by = wid4 & 31;
  const int wid = threadIdx.x >> 6, lane = threadIdx.x & 63;
  const int l = m + by * 4 + wid;
  const bool valid = (l < LL);
  if (valid) {
    const int c = lane & 31;
    const float* lg = leg + ((size_t)(l * MM2 + 127 + m)) * NT;
    const float* fp = ((lane >> 5) ? fwi : fwr) + (size_t)m * NT * NC + c;
    float a = 0.f;
    for (int t = 0; t < NT; t += 4) {
      const float4 b4 = *(const float4*)(lg + t);   // 16B-aligned broadcast
      a = fmaf(b4.x, fp[(t + 0) * NC], a);
      a = fmaf(b4.y, fp[(t + 1) * NC], a);
      a = fmaf(b4.z, fp[(t + 2) * NC], a);
      a = fmaf(b4.w, fp[(t + 3) * NC], a);
    }
    sf[wid][lane] = a;    // [stream*32 + c]
  }
  __syncthreads();        // all 4 waves reach (no early return above)
  if (!valid) return;
  const int oo = lane & 31;
  const int half = lane >> 5;
  const float s0 = (m > 0) ? 1.0f : 0.0f;
  const size_t bp = ((size_t)(l * MM2 + 127 + m) * NC) * NO + oo;
  const size_t bn = ((size_t)(l * MM2 + 127 - m) * NC) * NO + oo;
  const float* fr = &sf[wid][half * 16];        // real part, c = half*16+u
  const float* fi = &sf[wid][32 + half * 16];   // imag part
  float accA = 0.f, accB = 0.f;
#pragma unroll
  for (int u = 0; u < 16; ++u) {
    const size_t co = (size_t)(half * 16 + u) * NO;
    const float wrp = wr[bp + co];
    const float wrn = wr[bn + co];
    const float wip = wi[bp + co];
    const float win = wi[bn + co];
    const float fa = fr[u];
    const float fb = fi[u];
    const float wa = fmaf(s0, wrn, wrp);          // Wr+ + s0*Wr-
    const float wb = fmaf(s0, win, -wip);         // s0*Wi- - Wi+
    accA = fmaf(fa, wa, fmaf(fb, wb, accA));
    accB = fmaf(fa, wb, fmaf(-fb, wa, accB));
  }
  accA += __shfl_down(accA, 32);
  accB += __shfl_down(accB, 32);
  if (lane < 32) {
    ya[(size_t)(m * LL + l) * NO + oo] = accA;
    yb[(size_t)(m * LL + l) * NO + oo] = accB;
  }
}

// ---------------------------------------------------------------- K4: inverse Legendre -> Ut bf16
// Ut[r=(t*32+o)][k] : k=2m -> cos coeff, k=2m+1 -> sin coeff.  XCD swizzle on m.
DEVFN void k4_G(const float* __restrict__ leg, const float* __restrict__ ya,
                const float* __restrict__ yb, unsigned short* __restrict__ ut) {
  const int fid  = blockIdx.x + (int)blockIdx.y * 128;   // grid (128,8) -> 0..1023
  const int wid4 = (fid & 7) * 128 + (fid >> 3);         // per-XCD m-chunk of 16
  const int m = wid4 >> 3;
  const int o = threadIdx.x & 31;
  const int tq = threadIdx.x >> 5;
  const int t0 = (wid4 & 7) * 32 + tq * 4;
  float aa[4] = {}, bb[4] = {};
#pragma unroll 4
  for (int l = m; l < LL; ++l) {
    const float4 g = *(const float4*)(leg + ((size_t)(l * MM2 + 127 + m)) * NT + t0);
    const float yav = ya[(m * LL + l) * NO + o];
    const float ybv = yb[(m * LL + l) * NO + o];
    aa[0] = fmaf(g.x, yav, aa[0]);  bb[0] = fmaf(g.x, ybv, bb[0]);
    aa[1] = fmaf(g.y, yav, aa[1]);  bb[1] = fmaf(g.y, ybv, bb[1]);
    aa[2] = fmaf(g.z, yav, aa[2]);  bb[2] = fmaf(g.z, ybv, bb[2]);
    aa[3] = fmaf(g.w, yav, aa[3]);  bb[3] = fmaf(g.w, ybv, bb[3]);
  }
#pragma unroll
  for (int i = 0; i < 4; ++i) {
    const unsigned int pk = (unsigned int)f2bf(aa[i]) | ((unsigned int)f2bf(bb[i]) << 16);
    *(unsigned int*)&ut[((size_t)((t0 + i) * 32 + o)) * 256 + 2 * m] = pk;
  }
}

// ---------------------------------------------------------------- K5: inverse DFT via MFMA (A=vt)
// D[p][r] = sum_k vt[p][k] * ut[r][k];  out[o][t][p] = D,  r=t*32+o   (M=512,N=8192,K=256)
DEVFN void k5_mfma(const unsigned short* __restrict__ ut,
                   const unsigned short* __restrict__ vt,
                   float* __restrict__ out) {
  __shared__ unsigned short As[128 * 32];  // vt tile (p rows)
  __shared__ unsigned short Bs[128 * 32];  // ut tile (r rows)
  const int tid = threadIdx.x;
  const int p0 = blockIdx.x * 128;
  const int r0 = blockIdx.y * 128;
  const int wid = tid >> 6, lane = tid & 63;
  const int wm = wid & 1, wn = wid >> 1;
  v4f acc[4][4];
#pragma unroll
  for (int i = 0; i < 4; ++i)
#pragma unroll
    for (int j = 0; j < 4; ++j) {
      acc[i][j][0] = 0.f; acc[i][j][1] = 0.f; acc[i][j][2] = 0.f; acc[i][j][3] = 0.f;
    }
  const int lr = lane & 15, lk = (lane >> 4) * 8;
  for (int k0 = 0; k0 < 256; k0 += 32) {
#pragma unroll
    for (int s = 0; s < 2; ++s) {
      const int chunk = tid + s * 256;
      const int row = chunk >> 2, c16 = chunk & 3;
      *(uint4*)&As[row * 32 + c16 * 8] =
          *(const uint4*)&vt[(size_t)(p0 + row) * 256 + k0 + c16 * 8];
      *(uint4*)&Bs[row * 32 + c16 * 8] =
          *(const uint4*)&ut[(size_t)(r0 + row) * 256 + k0 + c16 * 8];
    }
    __syncthreads();
    v8s af[4], bf[4];
#pragma unroll
    for (int i = 0; i < 4; ++i) af[i] = *(const v8s*)&As[(wm * 64 + i * 16 + lr) * 32 + lk];
#pragma unroll
    for (int j = 0; j < 4; ++j) bf[j] = *(const v8s*)&Bs[(wn * 64 + j * 16 + lr) * 32 + lk];
#pragma unroll
    for (int i = 0; i < 4; ++i)
#pragma unroll
      for (int j = 0; j < 4; ++j)
        acc[i][j] = __builtin_amdgcn_mfma_f32_16x16x32_bf16(af[i], bf[j], acc[i][j], 0, 0, 0);
    __syncthreads();
  }
  const int lrow = (lane >> 4) * 4;
#pragma unroll
  for (int i = 0; i < 4; ++i) {
    const int pbase = p0 + wm * 64 + i * 16 + lrow;
#pragma unroll
    for (int j = 0; j < 4; ++j) {
      const int r = r0 + wn * 64 + j * 16 + lr;
      const int t = r >> 5, o = r & 31;
      float4 v = {acc[i][j][0], acc[i][j][1], acc[i][j][2], acc[i][j][3]};
      *(float4*)&out[((size_t)o * NT + t) * NP + pbase] = v;
    }
  }
}

// ---------------------------------------------------------------- launch
extern "C" void kernel_launch(void* const* d_in, const int* in_sizes, int n_in,
                              void* d_out, int out_size, void* d_ws, size_t ws_size,
                              hipStream_t stream) {
  const float* x   = (const float*)d_in[0];
  const float* wr  = (const float*)d_in[1];
  const float* wi  = (const float*)d_in[2];
  const float* leg = (const float*)d_in[3];
  const float* wg  = (const float*)d_in[4];
  float* out = (float*)d_out;

  unsigned short* tw1t = (unsigned short*)d_ws;     // 256*512   = 131072
  unsigned short* vt   = tw1t + 131072;             // 512*256   = 131072
  unsigned short* xb   = vt + 131072;               // 8192*512  = 4194304
  unsigned short* ut   = xb + 4194304;              // 8192*256  = 2097152
  float* fwr = (float*)(ut + 2097152);              // 128*256*32 = 1048576
  float* fwi = fwr + 1048576;
  float* ya  = fwi + 1048576;                       // 128*128*32 = 524288
  float* yb  = ya + 524288;                         // total ~22 MB

  hipLaunchKernelGGL(kp_prep, dim3(2560), dim3(256), 0, stream, x, tw1t, vt, xb);
  hipLaunchKernelGGL(k1_mfma, dim3(64, 4), dim3(256), 0, stream, xb, tw1t, wg, fwr, fwi);
  hipLaunchKernelGGL(k23, dim3(128, 32), dim3(256), 0, stream, leg, fwr, fwi, wr, wi, ya, yb);
  hipLaunchKernelGGL(k4_G, dim3(128, 8), dim3(256), 0, stream, leg, ya, yb, ut);
  hipLaunchKernelGGL(k5_mfma, dim3(4, 64), dim3(256), 0, stream, ut, vt, out);
}

// Round 2
// 363.211 us; speedup vs baseline: 1.1017x; 1.0774x over previous
//
#include <hip/hip_runtime.h>
#include <math.h>

#define DEVFN __global__ __launch_bounds__(256)

namespace {
constexpr int LL  = 128;   // L
constexpr int MM2 = 255;   // 2L-1
constexpr int NT  = 256;   // ntheta
constexpr int NP  = 512;   // nphi
constexpr int NC  = 32;    // C_IN
constexpr int NO  = 32;    // C_OUT
constexpr float TWO_PI = 6.283185307179586476925286766559f;
}

typedef short v8s __attribute__((ext_vector_type(8)));   // 8 bf16 (4 VGPRs)
typedef float v4f __attribute__((ext_vector_type(4)));   // 4 fp32 acc

__device__ inline unsigned short f2bf(float f) {
  unsigned int u = __float_as_uint(f);
  return (unsigned short)((u + 0x7FFFu + ((u >> 16) & 1u)) >> 16);  // RNE
}

// Balanced m-assignment: XCD k owns m in {8k..8k+7} U {120-8k..127-8k}.
// Work per (m) is (128-m); pairing m with 127-m makes per-XCD work constant
// while keeping the per-XCD fw footprint at 16 m (1 MB, L2-resident).
__device__ inline int m_of(int k, int mloc) {
  return (mloc < 8) ? (8 * k + mloc) : (120 - 8 * k + (mloc - 8));
}

// ---------------------------------------------------------------- KP: prep (twiddles + x transpose)
DEVFN void kp_prep(const float* __restrict__ x, unsigned short* __restrict__ tw1t,
                   unsigned short* __restrict__ vt, unsigned short* __restrict__ xb) {
  __shared__ float sm[32][65];
  const int bid = blockIdx.x;
  const int tid = threadIdx.x;
  const float phi = TWO_PI / (float)NP;
  if (bid < 512) {
    const int idx = bid * 256 + tid;  // 0..131071
    const float fs = TWO_PI / (float)NP;
    {
      const int n = idx >> 9, p = idx & 511;
      const int m = n >> 1;
      const int k = (m * p) & (NP - 1);
      float s, c;
      sincosf(phi * (float)k, &s, &c);
      tw1t[idx] = f2bf((n & 1) ? (-s * fs) : (c * fs));
    }
    {
      const int p = idx >> 8, k = idx & 255;
      const int m = k >> 1;
      const int kk = (m * p) & (NP - 1);
      float s, c;
      sincosf(phi * (float)kk, &s, &c);
      vt[idx] = f2bf((k & 1) ? s : c);
    }
  } else {
    const int q = bid - 512;           // 0..2047
    const int t = q >> 3;
    const int p0 = (q & 7) * 64;
#pragma unroll
    for (int i = 0; i < 8; ++i) {
      const int idx = tid + i * 256;
      const int p = idx >> 5, c = idx & 31;
      sm[c][p] = x[((size_t)t * NP + p0 + p) * NC + c];
    }
    __syncthreads();
    const int c = tid >> 3, pg = tid & 7;
    unsigned short pk[8];
#pragma unroll
    for (int u = 0; u < 8; ++u) pk[u] = f2bf(sm[c][pg * 8 + u]);
    *(uint4*)(xb + ((size_t)(t * 32 + c)) * NP + p0 + pg * 8) = *(const uint4*)pk;
  }
}

// ---------------------------------------------------------------- K1: forward DFT via MFMA
// C[r][n] = sum_p Xb[r][p] * tw1t[n][p];  fw{r,i}[m][t][c] = C * wg[t]
// M=8192, N=256, K=512.  Tile BM=128 x BN=64 -> grid (64,4) = 256 blocks (full GPU).
DEVFN void k1_mfma(const unsigned short* __restrict__ xb,
                   const unsigned short* __restrict__ tw1t,
                   const float* __restrict__ wg,
                   float* __restrict__ fwr, float* __restrict__ fwi) {
  __shared__ unsigned short As[128 * 32];
  __shared__ unsigned short Bs[64 * 32];
  const int tid = threadIdx.x;
  const int r0 = blockIdx.x * 128;
  const int n0 = blockIdx.y * 64;
  const int wid = tid >> 6, lane = tid & 63;
  const int wm = wid & 1, wn = wid >> 1;   // 2x2 waves, wave tile 64(M) x 32(N)
  v4f acc[4][2];
#pragma unroll
  for (int i = 0; i < 4; ++i)
#pragma unroll
    for (int j = 0; j < 2; ++j) {
      acc[i][j][0] = 0.f; acc[i][j][1] = 0.f; acc[i][j][2] = 0.f; acc[i][j][3] = 0.f;
    }
  const int lr = lane & 15, lk = (lane >> 4) * 8;
  for (int k0 = 0; k0 < 512; k0 += 32) {
#pragma unroll
    for (int s = 0; s < 3; ++s) {
      const int chunk = tid + s * 256;      // 768 chunks x 16B (A:512, B:256)
      if (chunk < 512) {
        const int row = chunk >> 2, c16 = chunk & 3;
        *(uint4*)&As[row * 32 + c16 * 8] =
            *(const uint4*)&xb[(size_t)(r0 + row) * 512 + k0 + c16 * 8];
      } else {
        const int bc = chunk - 512;
        const int row = bc >> 2, c16 = bc & 3;
        *(uint4*)&Bs[row * 32 + c16 * 8] =
            *(const uint4*)&tw1t[(size_t)(n0 + row) * 512 + k0 + c16 * 8];
      }
    }
    __syncthreads();
    v8s af[4], bf[2];
#pragma unroll
    for (int i = 0; i < 4; ++i) af[i] = *(const v8s*)&As[(wm * 64 + i * 16 + lr) * 32 + lk];
#pragma unroll
    for (int j = 0; j < 2; ++j) bf[j] = *(const v8s*)&Bs[(wn * 32 + j * 16 + lr) * 32 + lk];
#pragma unroll
    for (int i = 0; i < 4; ++i)
#pragma unroll
      for (int j = 0; j < 2; ++j)
        acc[i][j] = __builtin_amdgcn_mfma_f32_16x16x32_bf16(af[i], bf[j], acc[i][j], 0, 0, 0);
    __syncthreads();
  }
  const int lrow = (lane >> 4) * 4;
#pragma unroll
  for (int i = 0; i < 4; ++i) {
    const int rbase = r0 + wm * 64 + i * 16 + lrow;
    const int t = rbase >> 5, c0 = rbase & 31;
    const float w = wg[t];
#pragma unroll
    for (int j = 0; j < 2; ++j) {
      const int n = n0 + wn * 32 + j * 16 + lr;
      const int mI = n >> 1;
      float* dst = (n & 1) ? fwi : fwr;
      float4 v = {acc[i][j][0] * w, acc[i][j][1] * w, acc[i][j][2] * w, acc[i][j][3] * w};
      *(float4*)&dst[((size_t)mI * NT + t) * NC + c0] = v;
    }
  }
}

// ---------------------------------------------------------------- K23: fused flm + channel mix
// Register-blocked: one wave owns FOUR l-values of the same m.
// Phase 1: flm[c] reduction over t (lane = s*32 + c, s = re/im); each fw value
// loaded once serves 4 independent FMA chains (4x less L2 traffic, 4x ILP).
// Phase 2: weight contraction, 16 independent HBM load streams per u-step.
// Grid (128,8); balanced XCD swizzle via m_of().
__global__ __launch_bounds__(256, 2) void k23(
    const float* __restrict__ leg, const float* __restrict__ fwr,
    const float* __restrict__ fwi, const float* __restrict__ wr,
    const float* __restrict__ wi, float* __restrict__ ya,
    float* __restrict__ yb) {
  __shared__ float sf[4][4][64];   // [wid][li][s*32+c]
  const int fid = blockIdx.x + (int)blockIdx.y * 128;   // 0..1023
  const int xk  = fid & 7;          // XCD (round-robin dispatch)
  const int loc = fid >> 3;         // 0..127 within XCD
  const int m   = m_of(xk, loc >> 3);
  const int by  = loc & 7;
  const int wid = threadIdx.x >> 6, lane = threadIdx.x & 63;
  const int lb  = m + by * 16 + wid * 4;   // wave's base l (owns lb..lb+3)
  const bool wvalid = (lb < LL);
  if (wvalid) {
    const int c = lane & 31;
    const float* fp = ((lane >> 5) ? fwi : fwr) + (size_t)m * NT * NC + c;
    const int l0 = lb, l1 = min(lb + 1, LL - 1), l2 = min(lb + 2, LL - 1), l3 = min(lb + 3, LL - 1);
    const float* lg0 = leg + ((size_t)(l0 * MM2 + 127 + m)) * NT;
    const float* lg1 = leg + ((size_t)(l1 * MM2 + 127 + m)) * NT;
    const float* lg2 = leg + ((size_t)(l2 * MM2 + 127 + m)) * NT;
    const float* lg3 = leg + ((size_t)(l3 * MM2 + 127 + m)) * NT;
    float a0 = 0.f, a1 = 0.f, a2 = 0.f, a3 = 0.f;
#pragma unroll 2
    for (int t = 0; t < NT; t += 4) {
      const float f0 = fp[(t + 0) * NC];
      const float f1 = fp[(t + 1) * NC];
      const float f2 = fp[(t + 2) * NC];
      const float f3 = fp[(t + 3) * NC];
      const float4 b0 = *(const float4*)(lg0 + t);
      const float4 b1 = *(const float4*)(lg1 + t);
      const float4 b2 = *(const float4*)(lg2 + t);
      const float4 b3 = *(const float4*)(lg3 + t);
      a0 = fmaf(b0.x, f0, a0); a0 = fmaf(b0.y, f1, a0); a0 = fmaf(b0.z, f2, a0); a0 = fmaf(b0.w, f3, a0);
      a1 = fmaf(b1.x, f0, a1); a1 = fmaf(b1.y, f1, a1); a1 = fmaf(b1.z, f2, a1); a1 = fmaf(b1.w, f3, a1);
      a2 = fmaf(b2.x, f0, a2); a2 = fmaf(b2.y, f1, a2); a2 = fmaf(b2.z, f2, a2); a2 = fmaf(b2.w, f3, a2);
      a3 = fmaf(b3.x, f0, a3); a3 = fmaf(b3.y, f1, a3); a3 = fmaf(b3.z, f2, a3); a3 = fmaf(b3.w, f3, a3);
    }
    sf[wid][0][lane] = a0;
    sf[wid][1][lane] = a1;
    sf[wid][2][lane] = a2;
    sf[wid][3][lane] = a3;
  }
  __syncthreads();
  if (!wvalid) return;
  const int oo = lane & 31;
  const int half = lane >> 5;
  const float s0 = (m > 0) ? 1.0f : 0.0f;
  size_t bp[4], bn[4];
#pragma unroll
  for (int li = 0; li < 4; ++li) {
    const int le = min(lb + li, LL - 1);
    bp[li] = ((size_t)(le * MM2 + 127 + m) * NC) * NO + oo;
    bn[li] = ((size_t)(le * MM2 + 127 - m) * NC) * NO + oo;
  }
  float accA[4] = {}, accB[4] = {};
#pragma unroll
  for (int u = 0; u < 16; ++u) {
    const size_t co = (size_t)(half * 16 + u) * NO;
#pragma unroll
    for (int li = 0; li < 4; ++li) {
      const float wrp = wr[bp[li] + co];
      const float wrn = wr[bn[li] + co];
      const float wip = wi[bp[li] + co];
      const float win = wi[bn[li] + co];
      const float fa = sf[wid][li][half * 16 + u];        // broadcast (free)
      const float fb = sf[wid][li][32 + half * 16 + u];
      const float wa = fmaf(s0, wrn, wrp);          // Wr+ + s0*Wr-
      const float wb = fmaf(s0, win, -wip);         // s0*Wi- - Wi+
      accA[li] = fmaf(fa, wa, fmaf(fb, wb, accA[li]));
      accB[li] = fmaf(fa, wb, fmaf(-fb, wa, accB[li]));
    }
  }
#pragma unroll
  for (int li = 0; li < 4; ++li) {
    accA[li] += __shfl_down(accA[li], 32);
    accB[li] += __shfl_down(accB[li], 32);
  }
  if (lane < 32) {
#pragma unroll
    for (int li = 0; li < 4; ++li) {
      if (lb + li < LL) {
        ya[(size_t)(m * LL + lb + li) * NO + oo] = accA[li];
        yb[(size_t)(m * LL + lb + li) * NO + oo] = accB[li];
      }
    }
  }
}

// ---------------------------------------------------------------- K4: inverse Legendre -> Ut bf16
// Ut[r=(t*32+o)][k] : k=2m -> cos coeff, k=2m+1 -> sin coeff.  Balanced XCD swizzle.
DEVFN void k4_G(const float* __restrict__ leg, const float* __restrict__ ya,
                const float* __restrict__ yb, unsigned short* __restrict__ ut) {
  const int fid = blockIdx.x + (int)blockIdx.y * 128;   // grid (128,8) -> 0..1023
  const int xk  = fid & 7;
  const int loc = fid >> 3;          // 0..127
  const int m   = m_of(xk, loc >> 3);
  const int tc  = loc & 7;
  const int o = threadIdx.x & 31;
  const int tq = threadIdx.x >> 5;
  const int t0 = tc * 32 + tq * 4;
  float aa[4] = {}, bb[4] = {};
#pragma unroll 4
  for (int l = m; l < LL; ++l) {
    const float4 g = *(const float4*)(leg + ((size_t)(l * MM2 + 127 + m)) * NT + t0);
    const float yav = ya[(m * LL + l) * NO + o];
    const float ybv = yb[(m * LL + l) * NO + o];
    aa[0] = fmaf(g.x, yav, aa[0]);  bb[0] = fmaf(g.x, ybv, bb[0]);
    aa[1] = fmaf(g.y, yav, aa[1]);  bb[1] = fmaf(g.y, ybv, bb[1]);
    aa[2] = fmaf(g.z, yav, aa[2]);  bb[2] = fmaf(g.z, ybv, bb[2]);
    aa[3] = fmaf(g.w, yav, aa[3]);  bb[3] = fmaf(g.w, ybv, bb[3]);
  }
#pragma unroll
  for (int i = 0; i < 4; ++i) {
    const unsigned int pk = (unsigned int)f2bf(aa[i]) | ((unsigned int)f2bf(bb[i]) << 16);
    *(unsigned int*)&ut[((size_t)((t0 + i) * 32 + o)) * 256 + 2 * m] = pk;
  }
}

// ---------------------------------------------------------------- K5: inverse DFT via MFMA (A=vt)
// D[p][r] = sum_k vt[p][k] * ut[r][k];  out[o][t][p] = D,  r=t*32+o   (M=512,N=8192,K=256)
DEVFN void k5_mfma(const unsigned short* __restrict__ ut,
                   const unsigned short* __restrict__ vt,
                   float* __restrict__ out) {
  __shared__ unsigned short As[128 * 32];  // vt tile (p rows)
  __shared__ unsigned short Bs[128 * 32];  // ut tile (r rows)
  const int tid = threadIdx.x;
  const int p0 = blockIdx.x * 128;
  const int r0 = blockIdx.y * 128;
  const int wid = tid >> 6, lane = tid & 63;
  const int wm = wid & 1, wn = wid >> 1;
  v4f acc[4][4];
#pragma unroll
  for (int i = 0; i < 4; ++i)
#pragma unroll
    for (int j = 0; j < 4; ++j) {
      acc[i][j][0] = 0.f; acc[i][j][1] = 0.f; acc[i][j][2] = 0.f; acc[i][j][3] = 0.f;
    }
  const int lr = lane & 15, lk = (lane >> 4) * 8;
  for (int k0 = 0; k0 < 256; k0 += 32) {
#pragma unroll
    for (int s = 0; s < 2; ++s) {
      const int chunk = tid + s * 256;
      const int row = chunk >> 2, c16 = chunk & 3;
      *(uint4*)&As[row * 32 + c16 * 8] =
          *(const uint4*)&vt[(size_t)(p0 + row) * 256 + k0 + c16 * 8];
      *(uint4*)&Bs[row * 32 + c16 * 8] =
          *(const uint4*)&ut[(size_t)(r0 + row) * 256 + k0 + c16 * 8];
    }
    __syncthreads();
    v8s af[4], bf[4];
#pragma unroll
    for (int i = 0; i < 4; ++i) af[i] = *(const v8s*)&As[(wm * 64 + i * 16 + lr) * 32 + lk];
#pragma unroll
    for (int j = 0; j < 4; ++j) bf[j] = *(const v8s*)&Bs[(wn * 64 + j * 16 + lr) * 32 + lk];
#pragma unroll
    for (int i = 0; i < 4; ++i)
#pragma unroll
      for (int j = 0; j < 4; ++j)
        acc[i][j] = __builtin_amdgcn_mfma_f32_16x16x32_bf16(af[i], bf[j], acc[i][j], 0, 0, 0);
    __syncthreads();
  }
  const int lrow = (lane >> 4) * 4;
#pragma unroll
  for (int i = 0; i < 4; ++i) {
    const int pbase = p0 + wm * 64 + i * 16 + lrow;
#pragma unroll
    for (int j = 0; j < 4; ++j) {
      const int r = r0 + wn * 64 + j * 16 + lr;
      const int t = r >> 5, o = r & 31;
      float4 v = {acc[i][j][0], acc[i][j][1], acc[i][j][2], acc[i][j][3]};
      *(float4*)&out[((size_t)o * NT + t) * NP + pbase] = v;
    }
  }
}

// ---------------------------------------------------------------- launch
extern "C" void kernel_launch(void* const* d_in, const int* in_sizes, int n_in,
                              void* d_out, int out_size, void* d_ws, size_t ws_size,
                              hipStream_t stream) {
  const float* x   = (const float*)d_in[0];
  const float* wr  = (const float*)d_in[1];
  const float* wi  = (const float*)d_in[2];
  const float* leg = (const float*)d_in[3];
  const float* wg  = (const float*)d_in[4];
  float* out = (float*)d_out;

  unsigned short* tw1t = (unsigned short*)d_ws;     // 256*512   = 131072
  unsigned short* vt   = tw1t + 131072;             // 512*256   = 131072
  unsigned short* xb   = vt + 131072;               // 8192*512  = 4194304
  unsigned short* ut   = xb + 4194304;              // 8192*256  = 2097152
  float* fwr = (float*)(ut + 2097152);              // 128*256*32 = 1048576
  float* fwi = fwr + 1048576;
  float* ya  = fwi + 1048576;                       // 128*128*32 = 524288
  float* yb  = ya + 524288;                         // total ~22 MB

  hipLaunchKernelGGL(kp_prep, dim3(2560), dim3(256), 0, stream, x, tw1t, vt, xb);
  hipLaunchKernelGGL(k1_mfma, dim3(64, 4), dim3(256), 0, stream, xb, tw1t, wg, fwr, fwi);
  hipLaunchKernelGGL(k23, dim3(128, 8), dim3(256), 0, stream, leg, fwr, fwi, wr, wi, ya, yb);
  hipLaunchKernelGGL(k4_G, dim3(128, 8), dim3(256), 0, stream, leg, ya, yb, ut);
  hipLaunchKernelGGL(k5_mfma, dim3(4, 64), dim3(256), 0, stream, ut, vt, out);
}